// Round 14
// baseline (121.421 us; speedup 1.0000x reference)
//
#include <hip/hip_runtime.h>
#include <math.h>

#define NCLS 16
#define TS   64      // pair-tile side (64x64 pairs per work item)
#define CH   32      // D-chunk depth
#define PAD  36      // 144 B row pitch: every row 16B-aligned for ds_read_b128
#define NB   512
#define POISON_INT ((int)0xAAAAAAAA)

// global float4 loads at 4-byte-aligned addresses (class start is arbitrary)
typedef float vfloat4 __attribute__((ext_vector_type(4), aligned(4)));

struct WsG {
    int   done;               // last-block counter (poison-based CAS init)
    float classSum[NCLS];     // accumulated on poison base (-3e-13, negligible)
};

// ---------------- Single fused kernel ---------------------------------------
// R14: prep + mmd + finalize in ONE launch (R13 ledger: prep/finalize/gaps =
// ~22.7 us vs mmd 40.7). Each block computes ctl redundantly in ITS OWN LDS
// (no global ctl in the hot loop -- avoids R3's aliasing regression); classSum
// accumulates onto the 0xAA ws poison (-3.03e-13 fp32, harmless vs O(1e3)
// sums); done-counter base fixed via atomicCAS(poison->0) issued by every
// block BEFORE its exit add (atomics on one address serialize, first arrival
// is a CAS), so last-block detection works whether ws is poisoned or zeroed.
//
// Math (verified R11/R13): dist = n_i + n_j - 2<x_i,x_j> (Gram form); tiles
// ti<=tj only, per element f*(Kpp+Ktt-Kpt-Ktp), f=diag?1:2; diag aliases
// cols->rows. Staging tail (verified R7): quad vector-load ONLY if fully
// inside the class, else per-element clamp to n-1; rows>=n masked in epilogue
// (RBF exp amplifies any norm/dot mismatch -- R6 lesson). Norms accumulated
// in-register from staged operands (R13). `#pragma unroll 1` on dc/dg loops
// bounds the scheduler's hoisting window -> no spill (R7/R8: full unroll ->
// 256 VGPR + 60-105 MB scratch).
__global__ __launch_bounds__(256) void mmd_kernel(
    const float* __restrict__ P, const float* __restrict__ T,
    const int* __restrict__ gt, int V, int D,
    WsG* __restrict__ wsg, float* __restrict__ out)
{
    __shared__ float sPr[TS][PAD], sTr[TS][PAD];
    __shared__ float sPc[TS][PAD], sTc[TS][PAD];
    __shared__ float wsum[4];
    __shared__ int   sStarts[NCLS + 1], sCounts[NCLS], sTpc[NCLS],
                     sPairBase[NCLS + 1];
    __shared__ int   sLast;

    const int t  = threadIdx.x;
    const int tx = t & 15;   // cols tx + 16b, b=0..3
    const int ty = t >> 4;   // rows ty + 16a, a=0..3
    const int sd = t >> 3;   // staging dim 0..31
    const int qb = t & 7;    // staging pixel-quad base: quads qb and qb+8

    // ---- per-block ctl (redundant, LDS-resident) ----
    if (t < NCLS) {
        int lo = 0, hi = V;            // lower_bound of class id t in sorted gt
        while (lo < hi) {
            int mid = (lo + hi) >> 1;
            if (gt[mid] < t) lo = mid + 1; else hi = mid;
        }
        sStarts[t] = lo;
    }
    if (t == 0) sStarts[NCLS] = V;
    if (t == 64)                        // normalize done base: poison -> 0
        atomicCAS(&wsg->done, POISON_INT, 0);
    __syncthreads();
    if (t == 0) {
        int pb = 0;
        for (int c = 0; c < NCLS; ++c) {
            int n = sStarts[c + 1] - sStarts[c];
            sCounts[c] = n;
            int tp = (n + TS - 1) / TS;
            sTpc[c] = tp;
            sPairBase[c] = pb;
            pb += tp * (tp + 1) / 2;   // upper-triangular tile pairs only
        }
        sPairBase[NCLS] = pb;
    }
    __syncthreads();

    const int W = sPairBase[NCLS];
    float* classSum = wsg->classSum;

    const float invs[6] = {-0.25f, -0.1f, -0.05f, -0.025f, -0.0125f, -1.0f/120.0f};

    for (int w = blockIdx.x; w < W; w += gridDim.x) {
        int c = 0;
        while (sPairBase[c + 1] <= w) ++c;
        const int tp = sTpc[c];
        // triangular decode: row ti has (tp - ti) entries, tj = ti + rem
        int rem = w - sPairBase[c];
        int ti = 0;
        while (rem >= tp - ti) { rem -= (tp - ti); ++ti; }
        const int tj     = ti + rem;
        const bool diag  = (ti == tj);
        const int n      = sCounts[c];
        const int start  = sStarts[c];
        const int i0     = ti * TS;
        const int j0     = tj * TS;

        // relative quad bases within the class
        const int r0 = i0 + 4 * qb;
        const int r1 = i0 + 4 * qb + 32;
        const int c0 = j0 + 4 * qb;
        const int c1 = j0 + 4 * qb + 32;

        vfloat4 vPr0, vPr1, vTr0, vTr1, vPc0, vPc1, vTc0, vTc1;

        auto load_quad = [&](long off, int rb, vfloat4& vP, vfloat4& vT) {
            if (rb + 3 < n) {
                vP = *(const vfloat4*)&P[off + start + rb];
                vT = *(const vfloat4*)&T[off + start + rb];
            } else {
                int a0 = start + min(rb,     n - 1);
                int a1 = start + min(rb + 1, n - 1);
                int a2 = start + min(rb + 2, n - 1);
                int a3 = start + min(rb + 3, n - 1);
                vP = (vfloat4){P[off + a0], P[off + a1], P[off + a2], P[off + a3]};
                vT = (vfloat4){T[off + a0], T[off + a1], T[off + a2], T[off + a3]};
            }
        };
        auto issue_loads = [&](int dcc) {
            const long off = (long)(dcc + sd) * (long)V;
            load_quad(off, r0, vPr0, vTr0);
            load_quad(off, r1, vPr1, vTr1);
            if (!diag) {
                load_quad(off, c0, vPc0, vTc0);
                load_quad(off, c1, vPc1, vTc1);
            }
        };

        // diag tiles read cols from the row arrays (wave-uniform select)
        const float (*sCp)[PAD] = diag ? sPr : sPc;
        const float (*sCt)[PAD] = diag ? sTr : sTc;

        float dpp[4][4], dtt[4][4], dpt[4][4], dtp[4][4];
        float nPr[4], nTr[4], nPc[4], nTc[4];
        #pragma unroll
        for (int a = 0; a < 4; ++a) {
            nPr[a] = 0.f; nTr[a] = 0.f; nPc[a] = 0.f; nTc[a] = 0.f;
            #pragma unroll
            for (int b = 0; b < 4; ++b)
                { dpp[a][b] = 0.f; dtt[a][b] = 0.f; dpt[a][b] = 0.f; dtp[a][b] = 0.f; }
        }

        issue_loads(0);

        #pragma unroll 1
        for (int dc = 0; dc < D; dc += CH) {
            __syncthreads();   // previous chunk's LDS reads (and wsum) complete
            #pragma unroll
            for (int k = 0; k < 4; ++k) {
                sPr[4*qb +      k][sd] = vPr0[k];
                sPr[4*qb + 32 + k][sd] = vPr1[k];
                sTr[4*qb +      k][sd] = vTr0[k];
                sTr[4*qb + 32 + k][sd] = vTr1[k];
            }
            if (!diag) {
                #pragma unroll
                for (int k = 0; k < 4; ++k) {
                    sPc[4*qb +      k][sd] = vPc0[k];
                    sPc[4*qb + 32 + k][sd] = vPc1[k];
                    sTc[4*qb +      k][sd] = vTc0[k];
                    sTc[4*qb + 32 + k][sd] = vTc1[k];
                }
            }
            __syncthreads();
            if (dc + CH < D)
                issue_loads(dc + CH);   // prefetch next chunk; overlaps compute

            // NOT unrolled; all 16 reads issue before any FMA (one wait point)
            #pragma unroll 1
            for (int dg = 0; dg < CH; dg += 4) {
                float4 rP[4], rT[4], cP[4], cT[4];
                #pragma unroll
                for (int a = 0; a < 4; ++a) {
                    rP[a] = *(const float4*)&sPr[ty + 16*a][dg];
                    rT[a] = *(const float4*)&sTr[ty + 16*a][dg];
                    cP[a] = *(const float4*)&sCp[tx + 16*a][dg];
                    cT[a] = *(const float4*)&sCt[tx + 16*a][dg];
                }
                #pragma unroll
                for (int a = 0; a < 4; ++a)
                    #pragma unroll
                    for (int b = 0; b < 4; ++b)
                        dpp[a][b] += rP[a].x*cP[b].x + rP[a].y*cP[b].y
                                   + rP[a].z*cP[b].z + rP[a].w*cP[b].w;
                #pragma unroll
                for (int a = 0; a < 4; ++a)
                    #pragma unroll
                    for (int b = 0; b < 4; ++b)
                        dpt[a][b] += rP[a].x*cT[b].x + rP[a].y*cT[b].y
                                   + rP[a].z*cT[b].z + rP[a].w*cT[b].w;
                #pragma unroll
                for (int a = 0; a < 4; ++a)
                    #pragma unroll
                    for (int b = 0; b < 4; ++b)
                        dtt[a][b] += rT[a].x*cT[b].x + rT[a].y*cT[b].y
                                   + rT[a].z*cT[b].z + rT[a].w*cT[b].w;
                #pragma unroll
                for (int a = 0; a < 4; ++a)
                    #pragma unroll
                    for (int b = 0; b < 4; ++b)
                        dtp[a][b] += rT[a].x*cP[b].x + rT[a].y*cP[b].y
                                   + rT[a].z*cP[b].z + rT[a].w*cP[b].w;
                // in-register norms: self-dots of already-loaded operands
                #pragma unroll
                for (int a = 0; a < 4; ++a) {
                    nPr[a] += rP[a].x*rP[a].x + rP[a].y*rP[a].y
                            + rP[a].z*rP[a].z + rP[a].w*rP[a].w;
                    nTr[a] += rT[a].x*rT[a].x + rT[a].y*rT[a].y
                            + rT[a].z*rT[a].z + rT[a].w*rT[a].w;
                    nPc[a] += cP[a].x*cP[a].x + cP[a].y*cP[a].y
                            + cP[a].z*cP[a].z + cP[a].w*cP[a].w;
                    nTc[a] += cT[a].x*cT[a].x + cT[a].y*cT[a].y
                            + cT[a].z*cT[a].z + cT[a].w*cT[a].w;
                }
            }
        }

        // epilogue: distances via Gram form, weighted RBF sum (masked)
        const float f = diag ? 1.0f : 2.0f;
        float total = 0.0f;
        #pragma unroll
        for (int a = 0; a < 4; ++a) {
            const int ii = i0 + ty + 16*a;
            if (ii < n) {
                const float nPi = nPr[a];
                const float nTi = nTr[a];
                #pragma unroll
                for (int b = 0; b < 4; ++b) {
                    const int jj = j0 + tx + 16*b;
                    if (jj < n) {
                        const float nPj = nPc[b];
                        const float nTj = nTc[b];
                        float Dpp = nPi + nPj - 2.0f * dpp[a][b];
                        float Dtt = nTi + nTj - 2.0f * dtt[a][b];
                        float Dpt = nPi + nTj - 2.0f * dpt[a][b];
                        float Dtp = nTi + nPj - 2.0f * dtp[a][b];
                        float s6 = 0.0f;
                        #pragma unroll
                        for (int s = 0; s < 6; ++s) {
                            s6 += __expf(invs[s] * Dpp) + __expf(invs[s] * Dtt)
                                - __expf(invs[s] * Dpt) - __expf(invs[s] * Dtp);
                        }
                        total += f * s6;
                    }
                }
            }
        }

        // wave shuffle reduce (width 64), 4 wave leaders via LDS, 1 atomic
        #pragma unroll
        for (int off = 32; off > 0; off >>= 1)
            total += __shfl_down(total, off, 64);
        if ((t & 63) == 0) wsum[t >> 6] = total;
        __syncthreads();
        if (t == 0)
            atomicAdd(&classSum[c], wsum[0] + wsum[1] + wsum[2] + wsum[3]);
    }

    // ---- fused finalize: last-of-512 block computes the scalar loss ----
    __threadfence();   // release: classSum adds visible before done-add
    if (t == 0) {
        int prev = atomicAdd(&wsg->done, 1);
        sLast = (prev == (int)gridDim.x - 1);
    }
    __syncthreads();
    if (sLast && t == 0) {
        __threadfence();   // acquire
        float loss = 0.0f;
        int k = 0;
        for (int c = 0; c < NCLS; ++c) {
            int n = sCounts[c];
            if (n > 0) {
                ++k;
                float s = __hip_atomic_load(&classSum[c], __ATOMIC_RELAXED,
                                            __HIP_MEMORY_SCOPE_AGENT);
                float fn    = (float)n;
                float denom = fmaxf(2.0f * fn * fn, 1.0f);
                float l     = s / denom;
                if (l > 0.0f) loss += sqrtf(l);
            }
        }
        out[0] = (k > 0) ? (loss / (float)k) : 0.0f;
    }
}

extern "C" void kernel_launch(void* const* d_in, const int* in_sizes, int n_in,
                              void* d_out, int out_size, void* d_ws, size_t ws_size,
                              hipStream_t stream) {
    const float* predict = (const float*)d_in[0];
    const float* target  = (const float*)d_in[1];
    const int*   gt      = (const int*)d_in[2];
    // d_in[3] = ignore_mask: all-True, unused by the reference math.

    const int V = in_sizes[2];        // B*H*W = 4096
    const int D = in_sizes[0] / V;    // C = 128

    WsG* wsg = (WsG*)d_ws;

    mmd_kernel<<<NB, 256, 0, stream>>>(predict, target, gt, V, D,
                                       wsg, (float*)d_out);
}